// Round 1
// baseline (2766.424 us; speedup 1.0000x reference)
//
#include <hip/hip_runtime.h>
#include <cmath>

// Shapes (fixed by the problem)
#define AT 225      // Z*Y*X anchors
#define NP 128      // points per sample
#define MT 1024     // B*T
#define NSEL 8
#define HD 64

// workspace float offsets
#define SZ_VOX  (1024u*64u*225u)      // 14,745,600  vox[m][h][a]
#define SZ_C1   (1024u*96u*63u)       // 6,193,152   c1[m][o][p]
#define SZ_C2   (1024u*128u*5u)       // 655,360     c2[m][o][zo]
#define SZ_VV   (1024u*64u)           // 65,536
#define SZ_XWI  (1024u*256u)          // 262,144
#define SZ_W1T  (64u*27u*96u)         // 165,888
#define SZ_W2T  (96u*27u*128u)        // 331,776
#define SZ_W3T  (640u*64u)            // 40,960

__device__ __forceinline__ float sigm(float x) { return 1.0f / (1.0f + expf(-x)); }

// ---------------------------------------------------------------- transpose
// w1t[(c*27+tap)*96 + o] = w1[o][c][tap]   (96,64,27)
// w2t[(c*27+tap)*128+ o] = w2[o][c][tap]   (128,96,27)
// w3t[k*64 + u]          = w3[u][k]        (64,640)
__global__ __launch_bounds__(256) void k_transpose(
    const float* __restrict__ w1, const float* __restrict__ w2,
    const float* __restrict__ w3,
    float* __restrict__ w1t, float* __restrict__ w2t, float* __restrict__ w3t)
{
    int idx = blockIdx.x * 256 + threadIdx.x;
    if (idx < (int)SZ_W1T) {
        int o = idx % 96, r = idx / 96;            // r = c*27+tap
        w1t[idx] = w1[o * 1728 + r];
    } else if (idx < (int)(SZ_W1T + SZ_W2T)) {
        int k = idx - SZ_W1T;
        int o = k % 128, r = k / 128;
        w2t[k] = w2[o * 2592 + r];
    } else if (idx < (int)(SZ_W1T + SZ_W2T + SZ_W3T)) {
        int k = idx - (SZ_W1T + SZ_W2T);
        int u = k & 63, r = k >> 6;
        w3t[k] = w3[u * 640 + r];
    }
}

// ---------------------------------------------------------------- pointnet
// per block: one m. 256 threads = 32 groups of 8 lanes; group handles one anchor,
// lane li handles neighbor slot li.
__global__ __launch_bounds__(256) void k_pointnet(
    const float* __restrict__ x, const float* __restrict__ g_loc,
    const float* __restrict__ w1, const float* __restrict__ b1,
    const float* __restrict__ w2, const float* __restrict__ b2,
    const float* __restrict__ w3, const float* __restrict__ b3,
    const float* __restrict__ aw, const float* __restrict__ ab,
    float* __restrict__ vox, float* __restrict__ attn_out)
{
    const int m = blockIdx.x;
    const int tid = threadIdx.x;
    __shared__ float pts[5][NP];            // component-major points
    __shared__ float dmat[32 * 136];        // per-group padded distance buf (li*17+r)

    for (int idx = tid; idx < NP * 5; idx += 256) {
        int n = idx / 5, c = idx % 5;
        pts[c][n] = x[m * (NP * 5) + idx];
    }
    __syncthreads();

    const float gx = g_loc[m * 2 + 0], gy = g_loc[m * 2 + 1];
    const int grp = tid >> 3, li = tid & 7;

    for (int ca = 0; ca < 256; ca += 32) {
        const int a = ca + grp;
        const bool active = (a < AT);
        const int aa = active ? a : (AT - 1);
        const int azi = aa / 25, ar = aa % 25, ayi = ar / 5, axi = ar % 5;
        const float fx = ((float)axi - 2.0f) * 0.2f + gx;
        const float fy = ((float)ayi - 2.0f) * 0.2f + gy;
        const float fz = (float)azi * 0.22f + 0.1f;
        const float sa = fx * fx + fy * fy + fz * fz;

        // distances: lane li covers points [li*16, li*16+16)
        #pragma unroll
        for (int r = 0; r < 16; ++r) {
            int n = li * 16 + r;
            float px = pts[0][n], py = pts[1][n], pz = pts[2][n];
            float d = sa - 2.0f * (fx * px + fy * py + fz * pz)
                        + (px * px + py * py + pz * pz);
            dmat[grp * 136 + li * 17 + r] = d;
        }
        // 8 rounds of stable min-selection (matches lax.top_k tie order)
        int nidx = 0;
        for (int j = 0; j < NSEL; ++j) {
            float best = 1e30f; int bidx = 0;
            #pragma unroll
            for (int r = 0; r < 16; ++r) {
                float v = dmat[grp * 136 + li * 17 + r];
                int n = li * 16 + r;
                if (v < best) { best = v; bidx = n; }
            }
            #pragma unroll
            for (int off = 1; off < 8; off <<= 1) {
                float ov = __shfl_xor(best, off);
                int   oi = __shfl_xor(bidx, off);
                if (ov < best || (ov == best && oi < bidx)) { best = ov; bidx = oi; }
            }
            if (li == j) nidx = bidx;
            if ((bidx >> 4) == li) dmat[grp * 136 + li * 17 + (bidx & 15)] = 1e30f;
        }

        // gather neighbor nidx
        float in0 = pts[0][nidx] - fx;
        float in1 = pts[1][nidx] - fy;
        float in2 = pts[2][nidx] - fz;
        float in3 = pts[3][nidx];
        float in4 = pts[4][nidx];

        // MLP 5->16->32->64 ; weights wave-uniform -> scalar loads
        float f1v[16];
        #pragma unroll
        for (int j = 0; j < 16; ++j) {
            float s = b1[j];
            s += in0 * w1[0 * 16 + j] + in1 * w1[1 * 16 + j] + in2 * w1[2 * 16 + j]
               + in3 * w1[3 * 16 + j] + in4 * w1[4 * 16 + j];
            f1v[j] = fmaxf(s, 0.0f);
        }
        float f2v[32];
        #pragma unroll
        for (int j = 0; j < 32; ++j) {
            float s = b2[j];
            #pragma unroll
            for (int i = 0; i < 16; ++i) s += f1v[i] * w2[i * 32 + j];
            f2v[j] = fmaxf(s, 0.0f);
        }
        float f3v[64];
        #pragma unroll
        for (int j = 0; j < 64; ++j) {
            float s = b3[j];
            #pragma unroll
            for (int i = 0; i < 32; ++i) s += f2v[i] * w3[i * 64 + j];
            f3v[j] = fmaxf(s, 0.0f);
        }
        // attention score + softmax over the 8 lanes of the group
        float sc = ab[0];
        #pragma unroll
        for (int h = 0; h < 64; ++h) sc += f3v[h] * aw[h];
        float mx = sc;
        #pragma unroll
        for (int off = 1; off < 8; off <<= 1) mx = fmaxf(mx, __shfl_xor(mx, off));
        float e = expf(sc - mx);
        float den = e;
        #pragma unroll
        for (int off = 1; off < 8; off <<= 1) den += __shfl_xor(den, off);
        float at = e / den;

        if (active) attn_out[(m * AT + a) * NSEL + li] = at;

        // weighted sum across the 8 lanes (butterfly -> all lanes hold total)
        #pragma unroll
        for (int h = 0; h < 64; ++h) {
            float v = at * f3v[h];
            #pragma unroll
            for (int off = 1; off < 8; off <<= 1) v += __shfl_xor(v, off);
            f3v[h] = v;
        }
        if (active) {
            #pragma unroll
            for (int hh = 0; hh < 8; ++hh) {
                int h = li * 8 + hh;
                vox[(m * 64 + h) * AT + a] = f3v[h];
            }
        }
    }
}

// ---------------------------------------------------------------- conv1
// in vox[m][64][225] -> out c1[m][96][63]; thread tile 6o x 4pos; c-chunks of 2.
__global__ __launch_bounds__(256) void k_conv1(
    const float* __restrict__ vox, const float* __restrict__ w1t,
    const float* __restrict__ b1, float* __restrict__ out)
{
    const int m = blockIdx.x;
    const int tid = threadIdx.x;
    const int pt = tid & 15, ot = tid >> 4;     // 16 x 16
    const int o0 = ot * 6;
    const int p0 = pt * 4;

    __shared__ float wbuf[2 * 27 * 96];   // [c2][tap][96]
    __shared__ float inbuf[2 * 225];      // [c2][pos225]

    int base[4]; bool valid[4];
    #pragma unroll
    for (int pp = 0; pp < 4; ++pp) {
        int p = p0 + pp;
        valid[pp] = (p < 63);
        if (p > 62) p = 62;
        int zo = p / 9, r = p % 9, yo = r / 3, xo = r % 3;
        base[pp] = zo * 25 + yo * 5 + xo;
    }

    float acc[6][4];
    #pragma unroll
    for (int i = 0; i < 6; ++i)
        #pragma unroll
        for (int j = 0; j < 4; ++j) acc[i][j] = 0.0f;

    for (int cc = 0; cc < 32; ++cc) {      // c chunk of 2
        __syncthreads();
        for (int idx = tid; idx < 2 * 27 * 96; idx += 256)
            wbuf[idx] = w1t[cc * (2 * 27 * 96) + idx];
        for (int idx = tid; idx < 2 * 225; idx += 256)
            inbuf[idx] = vox[(m * 64 + cc * 2) * 225 + idx];
        __syncthreads();

        #pragma unroll
        for (int c2 = 0; c2 < 2; ++c2) {
            #pragma unroll
            for (int tap = 0; tap < 27; ++tap) {
                const int dz = tap / 9, dyx = tap % 9, dy = dyx / 3, dx = dyx % 3;
                const int toff = dz * 25 + dy * 5 + dx;
                const float2* wrow = (const float2*)&wbuf[(c2 * 27 + tap) * 96 + o0];
                float2 wa = wrow[0], wb = wrow[1], wc = wrow[2];
                float iv[4];
                #pragma unroll
                for (int pp = 0; pp < 4; ++pp) iv[pp] = inbuf[c2 * 225 + base[pp] + toff];
                #pragma unroll
                for (int pp = 0; pp < 4; ++pp) {
                    acc[0][pp] = fmaf(wa.x, iv[pp], acc[0][pp]);
                    acc[1][pp] = fmaf(wa.y, iv[pp], acc[1][pp]);
                    acc[2][pp] = fmaf(wb.x, iv[pp], acc[2][pp]);
                    acc[3][pp] = fmaf(wb.y, iv[pp], acc[3][pp]);
                    acc[4][pp] = fmaf(wc.x, iv[pp], acc[4][pp]);
                    acc[5][pp] = fmaf(wc.y, iv[pp], acc[5][pp]);
                }
            }
        }
    }
    #pragma unroll
    for (int oo = 0; oo < 6; ++oo) {
        float bias = b1[o0 + oo];
        #pragma unroll
        for (int pp = 0; pp < 4; ++pp) {
            if (valid[pp])
                out[m * (96 * 63) + (o0 + oo) * 63 + (p0 + pp)] =
                    fmaxf(acc[oo][pp] + bias, 0.0f);
        }
    }
}

// ---------------------------------------------------------------- conv2
// in c1[m][96][63] -> out c2[m][128][5]; 2 m per block; thread = (mm, o).
__global__ __launch_bounds__(256) void k_conv2(
    const float* __restrict__ c1, const float* __restrict__ w2t,
    const float* __restrict__ b2, float* __restrict__ out)
{
    const int tid = threadIdx.x;
    const int mm = tid >> 7, o = tid & 127;
    const int m0 = blockIdx.x * 2;
    __shared__ float inb[2][96 * 63];
    for (int idx = tid; idx < 2 * 96 * 63; idx += 256)
        inb[idx / (96 * 63)][idx % (96 * 63)] = c1[m0 * (96 * 63) + idx];
    __syncthreads();

    float acc[5] = {0, 0, 0, 0, 0};
    for (int c = 0; c < 96; ++c) {
        #pragma unroll
        for (int tap = 0; tap < 27; ++tap) {
            const int dz = tap / 9, r9 = tap % 9;
            float w = w2t[(c * 27 + tap) * 128 + o];
            #pragma unroll
            for (int zo = 0; zo < 5; ++zo)
                acc[zo] = fmaf(w, inb[mm][c * 63 + (zo + dz) * 9 + r9], acc[zo]);
        }
    }
    float bias = b2[o];
    #pragma unroll
    for (int zo = 0; zo < 5; ++zo)
        out[(m0 + mm) * (128 * 5) + o * 5 + zo] = fmaxf(acc[zo] + bias, 0.0f);
}

// ---------------------------------------------------------------- conv3
// in c2[m][128][5] -> vv[m][64]; 4 m per block; thread = (mm, u). No relu.
__global__ __launch_bounds__(256) void k_conv3(
    const float* __restrict__ c2, const float* __restrict__ w3t,
    const float* __restrict__ b3, float* __restrict__ vv)
{
    const int tid = threadIdx.x;
    const int mm = tid >> 6, u = tid & 63;
    const int m0 = blockIdx.x * 4;
    __shared__ float inb[4][640];
    for (int idx = tid; idx < 4 * 640; idx += 256)
        inb[idx / 640][idx % 640] = c2[m0 * 640 + idx];
    __syncthreads();
    float acc = b3[u];
    for (int k = 0; k < 640; ++k)
        acc = fmaf(inb[mm][k], w3t[k * 64 + u], acc);
    vv[(m0 + mm) * 64 + u] = acc;
}

// ---------------------------------------------------------------- x @ Wi + b
__global__ __launch_bounds__(256) void k_xwi(
    const float* __restrict__ vv, const float* __restrict__ wi,
    const float* __restrict__ lb, float* __restrict__ xwi)
{
    const int m = blockIdx.x;
    const int j = threadIdx.x;
    float acc = lb[j];
    #pragma unroll
    for (int k = 0; k < 64; ++k)
        acc = fmaf(vv[m * 64 + k], wi[k * 256 + j], acc);
    xwi[m * 256 + j] = acc;
}

// ---------------------------------------------------------------- LSTM
// one block per batch b (independent across b). 256 threads: thread j owns
// gate column j (Wh[:,j] in 64 VGPRs); threads <64 own state unit u.
__global__ __launch_bounds__(256) void k_lstm(
    const float* __restrict__ xwi, const float* __restrict__ whg,
    const float* __restrict__ h0, const float* __restrict__ c0,
    float* __restrict__ avec, float* __restrict__ hn, float* __restrict__ cn)
{
    const int b = blockIdx.x;
    const int j = threadIdx.x;
    __shared__ float hbuf[64];
    __shared__ float gbuf[256];

    float wh[64];
    #pragma unroll
    for (int k = 0; k < 64; ++k) wh[k] = whg[k * 256 + j];

    if (j < 64) hbuf[j] = h0[b * 64 + j];
    float c = (j < 64) ? c0[b * 64 + j] : 0.0f;
    __syncthreads();

    for (int t = 0; t < 64; ++t) {
        float g = xwi[(b * 64 + t) * 256 + j];
        #pragma unroll
        for (int k = 0; k < 64; ++k) g = fmaf(hbuf[k], wh[k], g);
        gbuf[j] = g;
        __syncthreads();
        if (j < 64) {
            float gi = gbuf[j], gf = gbuf[64 + j], gg = gbuf[128 + j], go = gbuf[192 + j];
            c = sigm(gf) * c + sigm(gi) * tanhf(gg);
            float h = sigm(go) * tanhf(c);
            hbuf[j] = h;
            avec[(b * 64 + t) * 64 + j] = h;
        }
        __syncthreads();
    }
    if (j < 64) {
        hn[b * 64 + j] = hbuf[j];
        cn[b * 64 + j] = c;
    }
}

// ---------------------------------------------------------------- launch
extern "C" void kernel_launch(void* const* d_in, const int* in_sizes, int n_in,
                              void* d_out, int out_size, void* d_ws, size_t ws_size,
                              hipStream_t stream) {
    const float* x     = (const float*)d_in[0];
    const float* g_loc = (const float*)d_in[1];
    const float* h0    = (const float*)d_in[2];
    const float* c0    = (const float*)d_in[3];
    const float* pn_w1 = (const float*)d_in[4];
    const float* pn_b1 = (const float*)d_in[5];
    const float* pn_w2 = (const float*)d_in[6];
    const float* pn_b2 = (const float*)d_in[7];
    const float* pn_w3 = (const float*)d_in[8];
    const float* pn_b3 = (const float*)d_in[9];
    const float* aw    = (const float*)d_in[10];
    const float* ab    = (const float*)d_in[11];
    const float* vx_w1 = (const float*)d_in[12];
    const float* vx_b1 = (const float*)d_in[13];
    const float* vx_w2 = (const float*)d_in[14];
    const float* vx_b2 = (const float*)d_in[15];
    const float* vx_w3 = (const float*)d_in[16];
    const float* vx_b3 = (const float*)d_in[17];
    const float* lwi   = (const float*)d_in[18];
    const float* lwh   = (const float*)d_in[19];
    const float* lb    = (const float*)d_in[20];

    float* ws  = (float*)d_ws;
    float* vox = ws;
    float* c1  = vox + SZ_VOX;
    float* c2  = c1 + SZ_C1;
    float* vv  = c2 + SZ_C2;
    float* xwi = vv + SZ_VV;
    float* w1t = xwi + SZ_XWI;
    float* w2t = w1t + SZ_W1T;
    float* w3t = w2t + SZ_W2T;

    float* out   = (float*)d_out;
    float* avec  = out;                       // 65536
    float* attnw = out + 65536;               // 1843200
    float* hn    = out + 65536 + 1843200;     // 1024
    float* cn    = hn + 1024;                 // 1024

    k_transpose<<<2104, 256, 0, stream>>>(vx_w1, vx_w2, vx_w3, w1t, w2t, w3t);
    k_pointnet<<<1024, 256, 0, stream>>>(x, g_loc, pn_w1, pn_b1, pn_w2, pn_b2,
                                         pn_w3, pn_b3, aw, ab, vox, attnw);
    k_conv1<<<1024, 256, 0, stream>>>(vox, w1t, vx_b1, c1);
    k_conv2<<<512, 256, 0, stream>>>(c1, w2t, vx_b2, c2);
    k_conv3<<<256, 256, 0, stream>>>(c2, w3t, vx_b3, vv);
    k_xwi<<<1024, 256, 0, stream>>>(vv, lwi, lb, xwi);
    k_lstm<<<16, 256, 0, stream>>>(xwi, lwh, h0, c0, avec, hn, cn);
}

// Round 2
// 1003.006 us; speedup vs baseline: 2.7581x; 2.7581x over previous
//
#include <hip/hip_runtime.h>
#include <cmath>

// Shapes (fixed by the problem)
#define AT 225      // Z*Y*X anchors
#define NP 128      // points per sample
#define MT 1024     // B*T
#define NSEL 8
#define HD 64

// workspace float offsets
#define SZ_VOX  (1024u*64u*225u)      // 14,745,600  vox[m][h][a]
#define SZ_C1   (1024u*96u*63u)       // 6,193,152   c1[m][o][p]  (idx aliases this before conv1)
#define SZ_C2   (1024u*128u*5u)       // 655,360     c2[m][o][zo]
#define SZ_VV   (1024u*64u)           // 65,536
#define SZ_XWI  (1024u*256u)          // 262,144
#define SZ_W1T  (64u*27u*96u)         // 165,888
#define SZ_W2T  (96u*27u*128u)        // 331,776
#define SZ_W3T  (640u*64u)            // 40,960

__device__ __forceinline__ float sigm(float x) { return 1.0f / (1.0f + expf(-x)); }

// ---------------------------------------------------------------- transpose
__global__ __launch_bounds__(256) void k_transpose(
    const float* __restrict__ w1, const float* __restrict__ w2,
    const float* __restrict__ w3,
    float* __restrict__ w1t, float* __restrict__ w2t, float* __restrict__ w3t)
{
    int idx = blockIdx.x * 256 + threadIdx.x;
    if (idx < (int)SZ_W1T) {
        int o = idx % 96, r = idx / 96;            // r = c*27+tap
        w1t[idx] = w1[o * 1728 + r];
    } else if (idx < (int)(SZ_W1T + SZ_W2T)) {
        int k = idx - SZ_W1T;
        int o = k % 128, r = k / 128;
        w2t[k] = w2[o * 2592 + r];
    } else if (idx < (int)(SZ_W1T + SZ_W2T + SZ_W3T)) {
        int k = idx - (SZ_W1T + SZ_W2T);
        int u = k & 63, r = k >> 6;
        w3t[k] = w3[u * 640 + r];
    }
}

// ---------------------------------------------------------------- grouping
// one block per m; 32 groups of 8 lanes; group = one anchor; lane li owns
// points [li*16, li*16+16). Selection semantics identical to the round-0
// passing kernel (stable min, lower-index tie-break). Output: idx[row].
__global__ __launch_bounds__(256) void k_group(
    const float* __restrict__ x, const float* __restrict__ g_loc,
    int* __restrict__ idxbuf)
{
    const int m = blockIdx.x;
    const int tid = threadIdx.x;
    __shared__ float pts[3][NP];           // xyz only needed here

    for (int idx = tid; idx < NP * 5; idx += 256) {
        int n = idx / 5, c = idx % 5;
        if (c < 3) pts[c][n] = x[m * (NP * 5) + idx];
    }
    __syncthreads();

    const float gx = g_loc[m * 2 + 0], gy = g_loc[m * 2 + 1];
    const int grp = tid >> 3, li = tid & 7;

    for (int ca = 0; ca < 256; ca += 32) {
        const int a = ca + grp;
        const bool active = (a < AT);
        const int aa = active ? a : (AT - 1);
        const int azi = aa / 25, ar = aa % 25, ayi = ar / 5, axi = ar % 5;
        const float fx = ((float)axi - 2.0f) * 0.2f + gx;
        const float fy = ((float)ayi - 2.0f) * 0.2f + gy;
        const float fz = (float)azi * 0.22f + 0.1f;
        const float sa = fx * fx + fy * fy + fz * fz;

        float d[16];
        #pragma unroll
        for (int r = 0; r < 16; ++r) {
            int n = li * 16 + r;
            float px = pts[0][n], py = pts[1][n], pz = pts[2][n];
            d[r] = sa - 2.0f * (fx * px + fy * py + fz * pz)
                      + (px * px + py * py + pz * pz);
        }
        int nidx = 0;
        for (int j = 0; j < NSEL; ++j) {
            float best = 1e30f; int bidx = 0;
            #pragma unroll
            for (int r = 0; r < 16; ++r) {
                int n = li * 16 + r;
                if (d[r] < best) { best = d[r]; bidx = n; }
            }
            #pragma unroll
            for (int off = 1; off < 8; off <<= 1) {
                float ov = __shfl_xor(best, off);
                int   oi = __shfl_xor(bidx, off);
                if (ov < best || (ov == best && oi < bidx)) { best = ov; bidx = oi; }
            }
            if (li == j) nidx = bidx;
            if ((bidx >> 4) == li) {
                int slot = bidx & 15;
                #pragma unroll
                for (int r = 0; r < 16; ++r)
                    if (r == slot) d[r] = 1e30f;
            }
        }
        if (active) idxbuf[(m * AT + a) * NSEL + li] = nidx;
    }
}

// ---------------------------------------------------------------- MLP + attn
// one thread per row (m,a,ns); block=128 -> 16 anchors per block.
__global__ __launch_bounds__(128) void k_mlp(
    const float* __restrict__ x, const float* __restrict__ g_loc,
    const int* __restrict__ idxbuf,
    const float* __restrict__ w1, const float* __restrict__ b1,
    const float* __restrict__ w2, const float* __restrict__ b2,
    const float* __restrict__ w3, const float* __restrict__ b3,
    const float* __restrict__ aw, const float* __restrict__ ab,
    float* __restrict__ vox, float* __restrict__ attn_out)
{
    const int tid = threadIdx.x;
    const int row0 = blockIdx.x * 128;
    const int row = row0 + tid;

    __shared__ float pts[2][5][NP];        // up to 2 m's per block
    __shared__ float f3buf[128 * 65];      // [local_row][h], stride-65 pad
    __shared__ float sbuf[16 * 65];        // [a_local][h]

    const int m0 = row0 / 1800;
    const int m1 = (row0 + 127) / 1800;
    #pragma unroll
    for (int mm = 0; mm < 2; ++mm) {
        int mload = (mm == 0) ? m0 : m1;
        for (int i = tid; i < NP * 5; i += 128) {
            int n = i / 5, c = i % 5;
            pts[mm][c][n] = x[mload * (NP * 5) + i];
        }
    }
    __syncthreads();

    const int m = row / 1800;
    const int rr = row % 1800;
    const int a = rr >> 3;
    const int sel = (m == m0) ? 0 : 1;

    const int azi = a / 25, ar = a % 25, ayi = ar / 5, axi = ar % 5;
    const float gx = g_loc[m * 2 + 0], gy = g_loc[m * 2 + 1];
    const float fx = ((float)axi - 2.0f) * 0.2f + gx;
    const float fy = ((float)ayi - 2.0f) * 0.2f + gy;
    const float fz = (float)azi * 0.22f + 0.1f;

    const int nidx = idxbuf[row];
    const float in0 = pts[sel][0][nidx] - fx;
    const float in1 = pts[sel][1][nidx] - fy;
    const float in2 = pts[sel][2][nidx] - fz;
    const float in3 = pts[sel][3][nidx];
    const float in4 = pts[sel][4][nidx];

    float f1v[16];
    #pragma unroll
    for (int j = 0; j < 16; ++j) {
        float s = b1[j];
        s += in0 * w1[0 * 16 + j] + in1 * w1[1 * 16 + j] + in2 * w1[2 * 16 + j]
           + in3 * w1[3 * 16 + j] + in4 * w1[4 * 16 + j];
        f1v[j] = fmaxf(s, 0.0f);
    }
    float f2v[32];
    #pragma unroll
    for (int j = 0; j < 32; ++j) {
        float s = b2[j];
        #pragma unroll
        for (int i = 0; i < 16; ++i) s += f1v[i] * w2[i * 32 + j];
        f2v[j] = fmaxf(s, 0.0f);
    }

    // layer 3 in chunks of 8; park f3 in LDS; fold attention score on the fly
    float sc = ab[0];
    #pragma unroll
    for (int j0 = 0; j0 < 64; j0 += 8) {
        float t[8];
        #pragma unroll
        for (int jj = 0; jj < 8; ++jj) {
            float s = b3[j0 + jj];
            #pragma unroll
            for (int i = 0; i < 32; ++i) s += f2v[i] * w3[i * 64 + j0 + jj];
            t[jj] = fmaxf(s, 0.0f);
            sc += t[jj] * aw[j0 + jj];
        }
        #pragma unroll
        for (int jj = 0; jj < 8; ++jj)
            f3buf[tid * 65 + j0 + jj] = t[jj];
    }

    // softmax over the 8-lane group (same op order as round 0)
    float mx = sc;
    #pragma unroll
    for (int off = 1; off < 8; off <<= 1) mx = fmaxf(mx, __shfl_xor(mx, off));
    float e = expf(sc - mx);
    float den = e;
    #pragma unroll
    for (int off = 1; off < 8; off <<= 1) den += __shfl_xor(den, off);
    const float at = e / den;
    attn_out[row] = at;

    __syncthreads();

    // phase 2: lane li accumulates h = hh*8+li for its group's anchor
    const int lgrp = tid >> 3;            // block-local group 0..15
    const int li = tid & 7;
    const int wl = tid & 63;              // lane in wave
    float o[8];
    #pragma unroll
    for (int hh = 0; hh < 8; ++hh) o[hh] = 0.0f;
    #pragma unroll
    for (int ns = 0; ns < 8; ++ns) {
        float atn = __shfl(at, (wl >> 3) * 8 + ns);
        #pragma unroll
        for (int hh = 0; hh < 8; ++hh)
            o[hh] = fmaf(atn, f3buf[(lgrp * 8 + ns) * 65 + hh * 8 + li], o[hh]);
    }
    #pragma unroll
    for (int hh = 0; hh < 8; ++hh)
        sbuf[lgrp * 65 + hh * 8 + li] = o[hh];
    __syncthreads();

    // cooperative coalesced vox write: vox[(m*64+h)*225 + a]
    const int al = tid & 15, j = tid >> 4;       // 16 anchors x 8 h-slots
    const int ga = (row0 >> 3) + al;             // global anchor = m*225+a
    const int ma = ga / 225, aa2 = ga % 225;
    #pragma unroll
    for (int rep = 0; rep < 8; ++rep) {
        int h = j * 8 + rep;
        vox[(ma * 64 + h) * AT + aa2] = sbuf[al * 65 + h];
    }
}

// ---------------------------------------------------------------- conv1
__global__ __launch_bounds__(256) void k_conv1(
    const float* __restrict__ vox, const float* __restrict__ w1t,
    const float* __restrict__ b1, float* __restrict__ out)
{
    const int m = blockIdx.x;
    const int tid = threadIdx.x;
    const int pt = tid & 15, ot = tid >> 4;     // 16 x 16
    const int o0 = ot * 6;
    const int p0 = pt * 4;

    __shared__ float wbuf[2 * 27 * 96];   // [c2][tap][96]
    __shared__ float inbuf[2 * 225];      // [c2][pos225]

    int base[4]; bool valid[4];
    #pragma unroll
    for (int pp = 0; pp < 4; ++pp) {
        int p = p0 + pp;
        valid[pp] = (p < 63);
        if (p > 62) p = 62;
        int zo = p / 9, r = p % 9, yo = r / 3, xo = r % 3;
        base[pp] = zo * 25 + yo * 5 + xo;
    }

    float acc[6][4];
    #pragma unroll
    for (int i = 0; i < 6; ++i)
        #pragma unroll
        for (int j = 0; j < 4; ++j) acc[i][j] = 0.0f;

    for (int cc = 0; cc < 32; ++cc) {      // c chunk of 2
        __syncthreads();
        for (int idx = tid; idx < 2 * 27 * 96; idx += 256)
            wbuf[idx] = w1t[cc * (2 * 27 * 96) + idx];
        for (int idx = tid; idx < 2 * 225; idx += 256)
            inbuf[idx] = vox[(m * 64 + cc * 2) * 225 + idx];
        __syncthreads();

        #pragma unroll
        for (int c2 = 0; c2 < 2; ++c2) {
            #pragma unroll
            for (int tap = 0; tap < 27; ++tap) {
                const int dz = tap / 9, dyx = tap % 9, dy = dyx / 3, dx = dyx % 3;
                const int toff = dz * 25 + dy * 5 + dx;
                const float2* wrow = (const float2*)&wbuf[(c2 * 27 + tap) * 96 + o0];
                float2 wa = wrow[0], wb = wrow[1], wc = wrow[2];
                float iv[4];
                #pragma unroll
                for (int pp = 0; pp < 4; ++pp) iv[pp] = inbuf[c2 * 225 + base[pp] + toff];
                #pragma unroll
                for (int pp = 0; pp < 4; ++pp) {
                    acc[0][pp] = fmaf(wa.x, iv[pp], acc[0][pp]);
                    acc[1][pp] = fmaf(wa.y, iv[pp], acc[1][pp]);
                    acc[2][pp] = fmaf(wb.x, iv[pp], acc[2][pp]);
                    acc[3][pp] = fmaf(wb.y, iv[pp], acc[3][pp]);
                    acc[4][pp] = fmaf(wc.x, iv[pp], acc[4][pp]);
                    acc[5][pp] = fmaf(wc.y, iv[pp], acc[5][pp]);
                }
            }
        }
    }
    #pragma unroll
    for (int oo = 0; oo < 6; ++oo) {
        float bias = b1[o0 + oo];
        #pragma unroll
        for (int pp = 0; pp < 4; ++pp) {
            if (valid[pp])
                out[m * (96 * 63) + (o0 + oo) * 63 + (p0 + pp)] =
                    fmaxf(acc[oo][pp] + bias, 0.0f);
        }
    }
}

// ---------------------------------------------------------------- conv2
__global__ __launch_bounds__(256) void k_conv2(
    const float* __restrict__ c1, const float* __restrict__ w2t,
    const float* __restrict__ b2, float* __restrict__ out)
{
    const int tid = threadIdx.x;
    const int mm = tid >> 7, o = tid & 127;
    const int m0 = blockIdx.x * 2;
    __shared__ float inb[2][96 * 63];
    for (int idx = tid; idx < 2 * 96 * 63; idx += 256)
        inb[idx / (96 * 63)][idx % (96 * 63)] = c1[m0 * (96 * 63) + idx];
    __syncthreads();

    float acc[5] = {0, 0, 0, 0, 0};
    for (int c = 0; c < 96; ++c) {
        #pragma unroll
        for (int tap = 0; tap < 27; ++tap) {
            const int dz = tap / 9, r9 = tap % 9;
            float w = w2t[(c * 27 + tap) * 128 + o];
            #pragma unroll
            for (int zo = 0; zo < 5; ++zo)
                acc[zo] = fmaf(w, inb[mm][c * 63 + (zo + dz) * 9 + r9], acc[zo]);
        }
    }
    float bias = b2[o];
    #pragma unroll
    for (int zo = 0; zo < 5; ++zo)
        out[(m0 + mm) * (128 * 5) + o * 5 + zo] = fmaxf(acc[zo] + bias, 0.0f);
}

// ---------------------------------------------------------------- conv3
__global__ __launch_bounds__(256) void k_conv3(
    const float* __restrict__ c2, const float* __restrict__ w3t,
    const float* __restrict__ b3, float* __restrict__ vv)
{
    const int tid = threadIdx.x;
    const int mm = tid >> 6, u = tid & 63;
    const int m0 = blockIdx.x * 4;
    __shared__ float inb[4][640];
    for (int idx = tid; idx < 4 * 640; idx += 256)
        inb[idx / 640][idx % 640] = c2[m0 * 640 + idx];
    __syncthreads();
    float acc = b3[u];
    for (int k = 0; k < 640; ++k)
        acc = fmaf(inb[mm][k], w3t[k * 64 + u], acc);
    vv[(m0 + mm) * 64 + u] = acc;
}

// ---------------------------------------------------------------- x @ Wi + b
__global__ __launch_bounds__(256) void k_xwi(
    const float* __restrict__ vv, const float* __restrict__ wi,
    const float* __restrict__ lb, float* __restrict__ xwi)
{
    const int m = blockIdx.x;
    const int j = threadIdx.x;
    float acc = lb[j];
    #pragma unroll
    for (int k = 0; k < 64; ++k)
        acc = fmaf(vv[m * 64 + k], wi[k * 256 + j], acc);
    xwi[m * 256 + j] = acc;
}

// ---------------------------------------------------------------- LSTM
__global__ __launch_bounds__(256) void k_lstm(
    const float* __restrict__ xwi, const float* __restrict__ whg,
    const float* __restrict__ h0, const float* __restrict__ c0,
    float* __restrict__ avec, float* __restrict__ hn, float* __restrict__ cn)
{
    const int b = blockIdx.x;
    const int j = threadIdx.x;
    __shared__ float hbuf[64];
    __shared__ float gbuf[256];

    float wh[64];
    #pragma unroll
    for (int k = 0; k < 64; ++k) wh[k] = whg[k * 256 + j];

    if (j < 64) hbuf[j] = h0[b * 64 + j];
    float c = (j < 64) ? c0[b * 64 + j] : 0.0f;
    __syncthreads();

    for (int t = 0; t < 64; ++t) {
        float g = xwi[(b * 64 + t) * 256 + j];
        #pragma unroll
        for (int k = 0; k < 64; ++k) g = fmaf(hbuf[k], wh[k], g);
        gbuf[j] = g;
        __syncthreads();
        if (j < 64) {
            float gi = gbuf[j], gf = gbuf[64 + j], gg = gbuf[128 + j], go = gbuf[192 + j];
            c = sigm(gf) * c + sigm(gi) * tanhf(gg);
            float h = sigm(go) * tanhf(c);
            hbuf[j] = h;
            avec[(b * 64 + t) * 64 + j] = h;
        }
        __syncthreads();
    }
    if (j < 64) {
        hn[b * 64 + j] = hbuf[j];
        cn[b * 64 + j] = c;
    }
}

// ---------------------------------------------------------------- launch
extern "C" void kernel_launch(void* const* d_in, const int* in_sizes, int n_in,
                              void* d_out, int out_size, void* d_ws, size_t ws_size,
                              hipStream_t stream) {
    const float* x     = (const float*)d_in[0];
    const float* g_loc = (const float*)d_in[1];
    const float* h0    = (const float*)d_in[2];
    const float* c0    = (const float*)d_in[3];
    const float* pn_w1 = (const float*)d_in[4];
    const float* pn_b1 = (const float*)d_in[5];
    const float* pn_w2 = (const float*)d_in[6];
    const float* pn_b2 = (const float*)d_in[7];
    const float* pn_w3 = (const float*)d_in[8];
    const float* pn_b3 = (const float*)d_in[9];
    const float* aw    = (const float*)d_in[10];
    const float* ab    = (const float*)d_in[11];
    const float* vx_w1 = (const float*)d_in[12];
    const float* vx_b1 = (const float*)d_in[13];
    const float* vx_w2 = (const float*)d_in[14];
    const float* vx_b2 = (const float*)d_in[15];
    const float* vx_w3 = (const float*)d_in[16];
    const float* vx_b3 = (const float*)d_in[17];
    const float* lwi   = (const float*)d_in[18];
    const float* lwh   = (const float*)d_in[19];
    const float* lb    = (const float*)d_in[20];

    float* ws  = (float*)d_ws;
    float* vox = ws;
    float* c1  = vox + SZ_VOX;
    float* c2  = c1 + SZ_C1;
    float* vv  = c2 + SZ_C2;
    float* xwi = vv + SZ_VV;
    float* w1t = xwi + SZ_XWI;
    float* w2t = w1t + SZ_W1T;
    float* w3t = w2t + SZ_W2T;
    int*   idxb = (int*)c1;   // idx lives in the (not-yet-written) c1 region

    float* out   = (float*)d_out;
    float* avec  = out;                       // 65536
    float* attnw = out + 65536;               // 1843200
    float* hn    = out + 65536 + 1843200;     // 1024
    float* cn    = hn + 1024;                 // 1024

    k_transpose<<<2104, 256, 0, stream>>>(vx_w1, vx_w2, vx_w3, w1t, w2t, w3t);
    k_group<<<1024, 256, 0, stream>>>(x, g_loc, idxb);
    k_mlp<<<14400, 128, 0, stream>>>(x, g_loc, idxb, pn_w1, pn_b1, pn_w2, pn_b2,
                                     pn_w3, pn_b3, aw, ab, vox, attnw);
    k_conv1<<<1024, 256, 0, stream>>>(vox, w1t, vx_b1, c1);
    k_conv2<<<512, 256, 0, stream>>>(c1, w2t, vx_b2, c2);
    k_conv3<<<256, 256, 0, stream>>>(c2, w3t, vx_b3, vv);
    k_xwi<<<1024, 256, 0, stream>>>(vv, lwi, lb, xwi);
    k_lstm<<<16, 256, 0, stream>>>(xwi, lwh, h0, c0, avec, hn, cn);
}

// Round 3
// 633.179 us; speedup vs baseline: 4.3691x; 1.5841x over previous
//
#include <hip/hip_runtime.h>
#include <cmath>

// Shapes (fixed by the problem)
#define AT 225      // Z*Y*X anchors
#define NP 128      // points per sample
#define MT 1024     // B*T
#define NSEL 8
#define HD 64

// workspace float offsets
#define SZ_VOX  (1024u*64u*225u)      // 14,745,600  vox[m][h][a]
#define SZ_C1   (1024u*96u*63u)      // 6,193,152   c1[m][o][p]  (idx aliases this before conv1)
#define SZ_C2   (1024u*128u*5u)      // 655,360     c2[m][o][zo]
#define SZ_VV   (1024u*64u)          // 65,536
#define SZ_XWI  (1024u*256u)         // 262,144
#define SZ_W1T  (64u*27u*96u)        // 165,888 floats reserved; holds w1m (165,888 bf16)
#define SZ_W2T  (96u*27u*128u)       // 331,776
#define SZ_W3T  (640u*64u)           // 40,960

typedef __attribute__((ext_vector_type(8))) short bf16x8;
typedef __attribute__((ext_vector_type(4))) float f32x4;

__device__ __forceinline__ float sigm(float x) { return 1.0f / (1.0f + expf(-x)); }

__device__ __forceinline__ unsigned short f2bf(float f) {
    unsigned u = __float_as_uint(f);
    unsigned r = u + 0x7FFF + ((u >> 16) & 1);   // RNE
    return (unsigned short)(r >> 16);
}

// ---------------------------------------------------------------- transpose
// w1m: MFMA A-fragment pre-swizzle for conv1. Element (s,t,lane,j):
//   o = t*16 + (lane&15); k' = s*32 + (lane>>4)*8 + j; tap = k'>>6; c = k'&63
//   value = bf16(w1[o][c*27+tap]);  linear idx = ((s*6+t)*64+lane)*8+j
// w2t[(c*27+tap)*128+o] = w2[o][c][tap]   (128,96,27)
// w3t[k*64+u]           = w3[u][k]        (64,640)
__global__ __launch_bounds__(256) void k_transpose(
    const float* __restrict__ w1, const float* __restrict__ w2,
    const float* __restrict__ w3,
    unsigned short* __restrict__ w1m, float* __restrict__ w2t,
    float* __restrict__ w3t)
{
    int idx = blockIdx.x * 256 + threadIdx.x;
    if (idx < 20736) {
        int lane = idx & 63, r = idx >> 6;
        int t = r % 6, s = r / 6;
        int o = t * 16 + (lane & 15);
        int kb = s * 32 + (lane >> 4) * 8;
        unsigned int dw[4];
        #pragma unroll
        for (int jd = 0; jd < 4; ++jd) {
            int k0 = kb + 2 * jd, k1 = k0 + 1;
            int tap0 = k0 >> 6, c0 = k0 & 63;
            int tap1 = k1 >> 6, c1 = k1 & 63;
            unsigned short lo = f2bf(w1[o * 1728 + c0 * 27 + tap0]);
            unsigned short hi = f2bf(w1[o * 1728 + c1 * 27 + tap1]);
            dw[jd] = (unsigned)lo | ((unsigned)hi << 16);
        }
        uint4 v; v.x = dw[0]; v.y = dw[1]; v.z = dw[2]; v.w = dw[3];
        ((uint4*)w1m)[idx] = v;
    } else if (idx < (int)(20736 + SZ_W2T)) {
        int k = idx - 20736;
        int o = k % 128, r = k / 128;
        w2t[k] = w2[o * 2592 + r];
    } else if (idx < (int)(20736 + SZ_W2T + SZ_W3T)) {
        int k = idx - (20736 + SZ_W2T);
        int u = k & 63, r = k >> 6;
        w3t[k] = w3[u * 640 + r];
    }
}

// ---------------------------------------------------------------- grouping
__global__ __launch_bounds__(256) void k_group(
    const float* __restrict__ x, const float* __restrict__ g_loc,
    int* __restrict__ idxbuf)
{
    const int m = blockIdx.x;
    const int tid = threadIdx.x;
    __shared__ float pts[3][NP];

    for (int idx = tid; idx < NP * 5; idx += 256) {
        int n = idx / 5, c = idx % 5;
        if (c < 3) pts[c][n] = x[m * (NP * 5) + idx];
    }
    __syncthreads();

    const float gx = g_loc[m * 2 + 0], gy = g_loc[m * 2 + 1];
    const int grp = tid >> 3, li = tid & 7;

    for (int ca = 0; ca < 256; ca += 32) {
        const int a = ca + grp;
        const bool active = (a < AT);
        const int aa = active ? a : (AT - 1);
        const int azi = aa / 25, ar = aa % 25, ayi = ar / 5, axi = ar % 5;
        const float fx = ((float)axi - 2.0f) * 0.2f + gx;
        const float fy = ((float)ayi - 2.0f) * 0.2f + gy;
        const float fz = (float)azi * 0.22f + 0.1f;
        const float sa = fx * fx + fy * fy + fz * fz;

        float d[16];
        #pragma unroll
        for (int r = 0; r < 16; ++r) {
            int n = li * 16 + r;
            float px = pts[0][n], py = pts[1][n], pz = pts[2][n];
            d[r] = sa - 2.0f * (fx * px + fy * py + fz * pz)
                      + (px * px + py * py + pz * pz);
        }
        int nidx = 0;
        for (int j = 0; j < NSEL; ++j) {
            float best = 1e30f; int bidx = 0;
            #pragma unroll
            for (int r = 0; r < 16; ++r) {
                int n = li * 16 + r;
                if (d[r] < best) { best = d[r]; bidx = n; }
            }
            #pragma unroll
            for (int off = 1; off < 8; off <<= 1) {
                float ov = __shfl_xor(best, off);
                int   oi = __shfl_xor(bidx, off);
                if (ov < best || (ov == best && oi < bidx)) { best = ov; bidx = oi; }
            }
            if (li == j) nidx = bidx;
            if ((bidx >> 4) == li) {
                int slot = bidx & 15;
                #pragma unroll
                for (int r = 0; r < 16; ++r)
                    if (r == slot) d[r] = 1e30f;
            }
        }
        if (active) idxbuf[(m * AT + a) * NSEL + li] = nidx;
    }
}

// ---------------------------------------------------------------- MLP + attn
__global__ __launch_bounds__(128) void k_mlp(
    const float* __restrict__ x, const float* __restrict__ g_loc,
    const int* __restrict__ idxbuf,
    const float* __restrict__ w1, const float* __restrict__ b1,
    const float* __restrict__ w2, const float* __restrict__ b2,
    const float* __restrict__ w3, const float* __restrict__ b3,
    const float* __restrict__ aw, const float* __restrict__ ab,
    float* __restrict__ vox, float* __restrict__ attn_out)
{
    const int tid = threadIdx.x;
    const int row0 = blockIdx.x * 128;
    const int row = row0 + tid;

    __shared__ float pts[2][5][NP];
    __shared__ float f3buf[128 * 65];
    __shared__ float sbuf[16 * 65];

    const int m0 = row0 / 1800;
    const int m1 = (row0 + 127) / 1800;
    #pragma unroll
    for (int mm = 0; mm < 2; ++mm) {
        int mload = (mm == 0) ? m0 : m1;
        for (int i = tid; i < NP * 5; i += 128) {
            int n = i / 5, c = i % 5;
            pts[mm][c][n] = x[mload * (NP * 5) + i];
        }
    }
    __syncthreads();

    const int m = row / 1800;
    const int rr = row % 1800;
    const int a = rr >> 3;
    const int sel = (m == m0) ? 0 : 1;

    const int azi = a / 25, ar = a % 25, ayi = ar / 5, axi = ar % 5;
    const float gx = g_loc[m * 2 + 0], gy = g_loc[m * 2 + 1];
    const float fx = ((float)axi - 2.0f) * 0.2f + gx;
    const float fy = ((float)ayi - 2.0f) * 0.2f + gy;
    const float fz = (float)azi * 0.22f + 0.1f;

    const int nidx = idxbuf[row];
    const float in0 = pts[sel][0][nidx] - fx;
    const float in1 = pts[sel][1][nidx] - fy;
    const float in2 = pts[sel][2][nidx] - fz;
    const float in3 = pts[sel][3][nidx];
    const float in4 = pts[sel][4][nidx];

    float f1v[16];
    #pragma unroll
    for (int j = 0; j < 16; ++j) {
        float s = b1[j];
        s += in0 * w1[0 * 16 + j] + in1 * w1[1 * 16 + j] + in2 * w1[2 * 16 + j]
           + in3 * w1[3 * 16 + j] + in4 * w1[4 * 16 + j];
        f1v[j] = fmaxf(s, 0.0f);
    }
    float f2v[32];
    #pragma unroll
    for (int j = 0; j < 32; ++j) {
        float s = b2[j];
        #pragma unroll
        for (int i = 0; i < 16; ++i) s += f1v[i] * w2[i * 32 + j];
        f2v[j] = fmaxf(s, 0.0f);
    }

    float sc = ab[0];
    #pragma unroll
    for (int j0 = 0; j0 < 64; j0 += 8) {
        float t[8];
        #pragma unroll
        for (int jj = 0; jj < 8; ++jj) {
            float s = b3[j0 + jj];
            #pragma unroll
            for (int i = 0; i < 32; ++i) s += f2v[i] * w3[i * 64 + j0 + jj];
            t[jj] = fmaxf(s, 0.0f);
            sc += t[jj] * aw[j0 + jj];
        }
        #pragma unroll
        for (int jj = 0; jj < 8; ++jj)
            f3buf[tid * 65 + j0 + jj] = t[jj];
    }

    float mx = sc;
    #pragma unroll
    for (int off = 1; off < 8; off <<= 1) mx = fmaxf(mx, __shfl_xor(mx, off));
    float e = expf(sc - mx);
    float den = e;
    #pragma unroll
    for (int off = 1; off < 8; off <<= 1) den += __shfl_xor(den, off);
    const float at = e / den;
    attn_out[row] = at;

    __syncthreads();

    const int lgrp = tid >> 3;
    const int li = tid & 7;
    const int wl = tid & 63;
    float o[8];
    #pragma unroll
    for (int hh = 0; hh < 8; ++hh) o[hh] = 0.0f;
    #pragma unroll
    for (int ns = 0; ns < 8; ++ns) {
        float atn = __shfl(at, (wl >> 3) * 8 + ns);
        #pragma unroll
        for (int hh = 0; hh < 8; ++hh)
            o[hh] = fmaf(atn, f3buf[(lgrp * 8 + ns) * 65 + hh * 8 + li], o[hh]);
    }
    #pragma unroll
    for (int hh = 0; hh < 8; ++hh)
        sbuf[lgrp * 65 + hh * 8 + li] = o[hh];
    __syncthreads();

    const int al = tid & 15, j = tid >> 4;
    const int ga = (row0 >> 3) + al;
    const int ma = ga / 225, aa2 = ga % 225;
    #pragma unroll
    for (int rep = 0; rep < 8; ++rep) {
        int h = j * 8 + rep;
        vox[(ma * 64 + h) * AT + aa2] = sbuf[al * 65 + h];
    }
}

// ---------------------------------------------------------------- conv1 MFMA
// Per block: one image m. D[96 o][63 p] = W[96][1728] x I[1728][63], bf16 MFMA.
// K reordered: k' = tap*64 + c  ->  a 32-k step = fixed tap, 32 contiguous c.
// voxT[a][c] bf16 in LDS, row stride 66 (33 dwords == 1 mod 32 banks).
// B-frag read directly from voxT (4x ds_read_b32, no im2col, no K-loop barrier).
// A-frags streamed from pre-swizzled global w1m (coalesced dwordx4, L1-shared).
__global__ __launch_bounds__(256) void k_conv1m(
    const float* __restrict__ vox, const unsigned short* __restrict__ w1m,
    const float* __restrict__ b1, float* __restrict__ out)
{
    const int m = blockIdx.x;
    const int tid = threadIdx.x;
    __shared__ unsigned short voxT[225 * 66];

    for (int i = tid; i < 64 * 225; i += 256) {
        int c = i / 225, a = i - c * 225;
        voxT[a * 66 + c] = f2bf(vox[m * (64 * 225) + i]);
    }
    __syncthreads();

    const int wv = tid >> 6, lane = tid & 63;
    const int quad = lane >> 4, n = lane & 15;
    const int p = wv * 16 + n;
    const int pe = (p > 62) ? 62 : p;
    const int zo = pe / 9, pr = pe % 9, yo = pr / 3, xo = pr % 3;
    const int basep = zo * 25 + yo * 5 + xo;

    f32x4 acc[6];
    #pragma unroll
    for (int t = 0; t < 6; ++t) acc[t] = (f32x4){0.f, 0.f, 0.f, 0.f};

    const uint4* Aptr = (const uint4*)w1m;

    // B-frag address for step s: row = basep + toff(tap), col base = (s&1)*32 + quad*8
    auto loadB = [&](int s) -> uint4 {
        int tap = s >> 1;
        int dz = tap / 9, tr = tap % 9, dy = tr / 3, dx = tr % 3;
        int row = basep + dz * 25 + dy * 5 + dx;
        int bidx = row * 66 + (s & 1) * 32 + quad * 8;   // even ushort index
        const unsigned int* vp = (const unsigned int*)(voxT + bidx);
        uint4 r; r.x = vp[0]; r.y = vp[1]; r.z = vp[2]; r.w = vp[3];
        return r;
    };

    uint4 Acur[6], Anxt[6];
    #pragma unroll
    for (int t = 0; t < 6; ++t) Acur[t] = Aptr[t * 64 + lane];
    uint4 Bcur = loadB(0), Bnxt;

    for (int s = 0; s < 54; ++s) {
        if (s < 53) {
            Bnxt = loadB(s + 1);
            #pragma unroll
            for (int t = 0; t < 6; ++t)
                Anxt[t] = Aptr[((s + 1) * 6 + t) * 64 + lane];
        }
        bf16x8 bf = __builtin_bit_cast(bf16x8, Bcur);
        #pragma unroll
        for (int t = 0; t < 6; ++t) {
            bf16x8 af = __builtin_bit_cast(bf16x8, Acur[t]);
            acc[t] = __builtin_amdgcn_mfma_f32_16x16x32_bf16(af, bf, acc[t], 0, 0, 0);
        }
        #pragma unroll
        for (int t = 0; t < 6; ++t) Acur[t] = Anxt[t];
        Bcur = Bnxt;
    }

    if (p < 63) {
        #pragma unroll
        for (int t = 0; t < 6; ++t) {
            #pragma unroll
            for (int r = 0; r < 4; ++r) {
                int o = t * 16 + quad * 4 + r;
                out[m * (96 * 63) + o * 63 + p] = fmaxf(acc[t][r] + b1[o], 0.0f);
            }
        }
    }
}

// ---------------------------------------------------------------- conv2
__global__ __launch_bounds__(256) void k_conv2(
    const float* __restrict__ c1, const float* __restrict__ w2t,
    const float* __restrict__ b2, float* __restrict__ out)
{
    const int tid = threadIdx.x;
    const int mm = tid >> 7, o = tid & 127;
    const int m0 = blockIdx.x * 2;
    __shared__ float inb[2][96 * 63];
    for (int idx = tid; idx < 2 * 96 * 63; idx += 256)
        inb[idx / (96 * 63)][idx % (96 * 63)] = c1[m0 * (96 * 63) + idx];
    __syncthreads();

    float acc[5] = {0, 0, 0, 0, 0};
    for (int c = 0; c < 96; ++c) {
        #pragma unroll
        for (int tap = 0; tap < 27; ++tap) {
            const int dz = tap / 9, r9 = tap % 9;
            float w = w2t[(c * 27 + tap) * 128 + o];
            #pragma unroll
            for (int zo = 0; zo < 5; ++zo)
                acc[zo] = fmaf(w, inb[mm][c * 63 + (zo + dz) * 9 + r9], acc[zo]);
        }
    }
    float bias = b2[o];
    #pragma unroll
    for (int zo = 0; zo < 5; ++zo)
        out[(m0 + mm) * (128 * 5) + o * 5 + zo] = fmaxf(acc[zo] + bias, 0.0f);
}

// ---------------------------------------------------------------- conv3
__global__ __launch_bounds__(256) void k_conv3(
    const float* __restrict__ c2, const float* __restrict__ w3t,
    const float* __restrict__ b3, float* __restrict__ vv)
{
    const int tid = threadIdx.x;
    const int mm = tid >> 6, u = tid & 63;
    const int m0 = blockIdx.x * 4;
    __shared__ float inb[4][640];
    for (int idx = tid; idx < 4 * 640; idx += 256)
        inb[idx / 640][idx % 640] = c2[m0 * 640 + idx];
    __syncthreads();
    float acc = b3[u];
    for (int k = 0; k < 640; ++k)
        acc = fmaf(inb[mm][k], w3t[k * 64 + u], acc);
    vv[(m0 + mm) * 64 + u] = acc;
}

// ---------------------------------------------------------------- x @ Wi + b
__global__ __launch_bounds__(256) void k_xwi(
    const float* __restrict__ vv, const float* __restrict__ wi,
    const float* __restrict__ lb, float* __restrict__ xwi)
{
    const int m = blockIdx.x;
    const int j = threadIdx.x;
    float acc = lb[j];
    #pragma unroll
    for (int k = 0; k < 64; ++k)
        acc = fmaf(vv[m * 64 + k], wi[k * 256 + j], acc);
    xwi[m * 256 + j] = acc;
}

// ---------------------------------------------------------------- LSTM
__global__ __launch_bounds__(256) void k_lstm(
    const float* __restrict__ xwi, const float* __restrict__ whg,
    const float* __restrict__ h0, const float* __restrict__ c0,
    float* __restrict__ avec, float* __restrict__ hn, float* __restrict__ cn)
{
    const int b = blockIdx.x;
    const int j = threadIdx.x;
    __shared__ float hbuf[64];
    __shared__ float gbuf[256];

    float wh[64];
    #pragma unroll
    for (int k = 0; k < 64; ++k) wh[k] = whg[k * 256 + j];

    if (j < 64) hbuf[j] = h0[b * 64 + j];
    float c = (j < 64) ? c0[b * 64 + j] : 0.0f;
    __syncthreads();

    for (int t = 0; t < 64; ++t) {
        float g = xwi[(b * 64 + t) * 256 + j];
        #pragma unroll
        for (int k = 0; k < 64; ++k) g = fmaf(hbuf[k], wh[k], g);
        gbuf[j] = g;
        __syncthreads();
        if (j < 64) {
            float gi = gbuf[j], gf = gbuf[64 + j], gg = gbuf[128 + j], go = gbuf[192 + j];
            c = sigm(gf) * c + sigm(gi) * tanhf(gg);
            float h = sigm(go) * tanhf(c);
            hbuf[j] = h;
            avec[(b * 64 + t) * 64 + j] = h;
        }
        __syncthreads();
    }
    if (j < 64) {
        hn[b * 64 + j] = hbuf[j];
        cn[b * 64 + j] = c;
    }
}

// ---------------------------------------------------------------- launch
extern "C" void kernel_launch(void* const* d_in, const int* in_sizes, int n_in,
                              void* d_out, int out_size, void* d_ws, size_t ws_size,
                              hipStream_t stream) {
    const float* x     = (const float*)d_in[0];
    const float* g_loc = (const float*)d_in[1];
    const float* h0    = (const float*)d_in[2];
    const float* c0    = (const float*)d_in[3];
    const float* pn_w1 = (const float*)d_in[4];
    const float* pn_b1 = (const float*)d_in[5];
    const float* pn_w2 = (const float*)d_in[6];
    const float* pn_b2 = (const float*)d_in[7];
    const float* pn_w3 = (const float*)d_in[8];
    const float* pn_b3 = (const float*)d_in[9];
    const float* aw    = (const float*)d_in[10];
    const float* ab    = (const float*)d_in[11];
    const float* vx_w1 = (const float*)d_in[12];
    const float* vx_b1 = (const float*)d_in[13];
    const float* vx_w2 = (const float*)d_in[14];
    const float* vx_b2 = (const float*)d_in[15];
    const float* vx_w3 = (const float*)d_in[16];
    const float* vx_b3 = (const float*)d_in[17];
    const float* lwi   = (const float*)d_in[18];
    const float* lwh   = (const float*)d_in[19];
    const float* lb    = (const float*)d_in[20];

    float* ws  = (float*)d_ws;
    float* vox = ws;
    float* c1  = vox + SZ_VOX;
    float* c2  = c1 + SZ_C1;
    float* vv  = c2 + SZ_C2;
    float* xwi = vv + SZ_VV;
    float* w1r = xwi + SZ_XWI;            // region reserved SZ_W1T floats
    float* w2t = w1r + SZ_W1T;
    float* w3t = w2t + SZ_W2T;
    unsigned short* w1m = (unsigned short*)w1r;
    int*   idxb = (int*)c1;               // idx lives in the (not-yet-written) c1 region

    float* out   = (float*)d_out;
    float* avec  = out;                   // 65536
    float* attnw = out + 65536;           // 1843200
    float* hn    = out + 65536 + 1843200; // 1024
    float* cn    = hn + 1024;             // 1024

    k_transpose<<<1537, 256, 0, stream>>>(vx_w1, vx_w2, vx_w3, w1m, w2t, w3t);
    k_group<<<1024, 256, 0, stream>>>(x, g_loc, idxb);
    k_mlp<<<14400, 128, 0, stream>>>(x, g_loc, idxb, pn_w1, pn_b1, pn_w2, pn_b2,
                                     pn_w3, pn_b3, aw, ab, vox, attnw);
    k_conv1m<<<1024, 256, 0, stream>>>(vox, w1m, vx_b1, c1);
    k_conv2<<<512, 256, 0, stream>>>(c1, w2t, vx_b2, c2);
    k_conv3<<<256, 256, 0, stream>>>(c2, w3t, vx_b3, vv);
    k_xwi<<<1024, 256, 0, stream>>>(vv, lwi, lb, xwi);
    k_lstm<<<16, 256, 0, stream>>>(xwi, lwh, h0, c0, avec, hn, cn);
}